// Round 14
// baseline (324.779 us; speedup 1.0000x reference)
//
#include <hip/hip_runtime.h>
#include <hip/hip_fp16.h>

#define IND 14
#define INDP 16
#define HIDD 64
#define RB 512          // nodes per bucket (shift 9)
#define NB_MAX 256
#define BH_BLOCKS 256   // fewer, fatter blocks -> long per-bucket write runs
#define CAP 18432       // per-bucket pairs/csr capacity (mean 16384, sigma 128)
#define ROW1 20         // padded row stride for layer1 LDS tiles
#define DSTS (13 * 1024) // LDS dst-cache slots (chunk = 12500 -> 13 iters x 1024)

typedef unsigned int uint;
typedef unsigned short ushort;

__device__ __forceinline__ __half2 u2h2(uint u) { return *reinterpret_cast<__half2*>(&u); }

// fused: build h0p/h0h + single-pass bucket scatter (dst cached in LDS)
__global__ __launch_bounds__(1024) void bscat_fused(
        const float* __restrict__ x, const float* __restrict__ pos,
        float* __restrict__ h0p, __half* __restrict__ h0h, int N,
        const int* __restrict__ ei, int* __restrict__ gcur,
        uint* __restrict__ pairs, int E, int NB, int chunk) {
    __shared__ int cntS[NB_MAX];
    __shared__ int baseS[NB_MAX];
    __shared__ int dstS[DSTS];
    // --- h0 build (independent; grid-stride over N*INDP) ---
    int tot = N * INDP;
    for (int i = blockIdx.x * 1024 + threadIdx.x; i < tot; i += BH_BLOCKS * 1024) {
        int n = i >> 4, d = i & 15;
        float v = 0.0f;
        if (d < 11) v = x[n * 11 + d];
        else if (d < 14) v = pos[n * 3 + (d - 11)];
        h0p[i] = v;
        h0h[i] = __float2half(v);
    }
    // --- pass 1: count (dst stream -> LDS cache) ---
    if (threadIdx.x < NB_MAX) cntS[threadIdx.x] = 0;
    __syncthreads();
    int start = blockIdx.x * chunk;
    int end = min(start + chunk, E);
    int it = 0;
    for (int e = start + threadIdx.x; e < end; e += 1024, ++it) {
        int d = ei[E + e];
        dstS[it * 1024 + threadIdx.x] = d;
        atomicAdd(&cntS[d >> 9], 1);
    }
    __syncthreads();
    if (threadIdx.x < NB) {
        int c = cntS[threadIdx.x];
        baseS[threadIdx.x] = c ? atomicAdd(&gcur[threadIdx.x], c) : 0;
        cntS[threadIdx.x] = 0;   // reuse as local cursor
    }
    __syncthreads();
    // --- pass 2: scatter (src stream cold-read, dst from LDS) ---
    it = 0;
    for (int e = start + threadIdx.x; e < end; e += 1024, ++it) {
        int s = ei[e];
        int d = dstS[it * 1024 + threadIdx.x];
        int b = d >> 9;
        int p = atomicAdd(&cntS[b], 1) + baseS[b];
        pairs[(size_t)b * CAP + p] = ((uint)(d & (RB - 1)) << 17) | (uint)s;
    }
}

// block per bucket: LDS deg hist + scan -> rowseg(int2) + bucket-padded csr.
__global__ __launch_bounds__(1024) void csr_build(const uint* __restrict__ pairs,
                                                  const int* __restrict__ gcur,
                                                  int2* __restrict__ rowseg,
                                                  int* __restrict__ csr, int N) {
    __shared__ int s[RB];
    __shared__ int fillS[RB];
    __shared__ ushort localS[CAP];
    int b = blockIdx.x;
    int cnt = gcur[b];
    size_t base = (size_t)b * CAP;
    int t = threadIdx.x;
    if (t < RB) { s[t] = 0; fillS[t] = 0; }
    __syncthreads();
    for (int i = t; i < cnt; i += 1024) {
        int local = (int)(pairs[base + i] >> 17);
        localS[i] = (ushort)local;
        atomicAdd(&s[local], 1);
    }
    __syncthreads();
    for (int off = 1; off < RB; off <<= 1) {
        int v = 0;
        if (t < RB && t >= off) v = s[t - off];
        __syncthreads();
        if (t < RB) s[t] += v;
        __syncthreads();
    }
    int node0 = b << 9;
    if (t < RB) {
        int node = node0 + t;
        if (node < N)
            rowseg[node] = make_int2((int)base + (t ? s[t - 1] : 0), (int)base + s[t]);
    }
    __syncthreads();
    for (int i = t; i < cnt; i += 1024) {
        int local = localS[i];
        int src = (int)(pairs[base + i] & 0x1FFFFu);
        int p = atomicAdd(&fillS[local], 1);
        int segbase = local ? s[local - 1] : 0;
        csr[base + segbase + p] = src;
    }
}

// fused gather-mean(h0h fp16, packed hfma2) + layer1 GEMM; wave per node
__global__ __launch_bounds__(512) void agg_layer1(
        const float* __restrict__ h0p, const __half* __restrict__ h0h,
        const int2* __restrict__ rowseg, const int* __restrict__ csr,
        const float* __restrict__ W_l, const float* __restrict__ W_r,
        const float* __restrict__ b, float* __restrict__ h1f,
        __half* __restrict__ h1h, int N) {
    __shared__ float sWl[IND * HIDD];
    __shared__ float sWr[IND * HIDD];
    __shared__ float sA[8][ROW1];
    __shared__ float sS[8][ROW1];
    for (int i = threadIdx.x; i < IND * HIDD; i += 512) {
        sWl[i] = W_l[i];
        sWr[i] = W_r[i];
    }
    int w = threadIdx.x >> 6, t = threadIdx.x & 63;
    int node = blockIdx.x * 8 + w;
    if (node < N) {
        int2 seg = rowseg[node];
        int beg = seg.x, end = seg.y;
        int s = t >> 1, hf = t & 1;
        __half2 a[4];
#pragma unroll
        for (int j = 0; j < 4; ++j) a[j] = __float2half2_rn(0.0f);
        for (int cb = beg; cb < end; cb += 64) {
            int e0 = cb + s, e1 = e0 + 32;
            int i0 = csr[min(e0, end - 1)];
            int i1 = csr[min(e1, end - 1)];
            __half2 m0 = __float2half2_rn((e0 < end) ? 1.f : 0.f);
            __half2 m1 = __float2half2_rn((e1 < end) ? 1.f : 0.f);
            const uint4 v0 = *(const uint4*)(h0h + (size_t)i0 * INDP + hf * 8);
            const uint4 v1 = *(const uint4*)(h0h + (size_t)i1 * INDP + hf * 8);
            a[0] = __hfma2(u2h2(v0.x), m0, a[0]);
            a[1] = __hfma2(u2h2(v0.y), m0, a[1]);
            a[2] = __hfma2(u2h2(v0.z), m0, a[2]);
            a[3] = __hfma2(u2h2(v0.w), m0, a[3]);
            a[0] = __hfma2(u2h2(v1.x), m1, a[0]);
            a[1] = __hfma2(u2h2(v1.y), m1, a[1]);
            a[2] = __hfma2(u2h2(v1.z), m1, a[2]);
            a[3] = __hfma2(u2h2(v1.w), m1, a[3]);
        }
        float acc[8];
#pragma unroll
        for (int j = 0; j < 4; ++j) {
            float2 f = __half22float2(a[j]);
            acc[2 * j] = f.x;
            acc[2 * j + 1] = f.y;
        }
#pragma unroll
        for (int m = 2; m < 64; m <<= 1) {
#pragma unroll
            for (int j = 0; j < 8; ++j) acc[j] += __shfl_xor(acc[j], m, 64);
        }
        float invd = 1.0f / fmaxf((float)(end - beg), 1.0f);
        if (t < 2) {
#pragma unroll
            for (int j = 0; j < 8; ++j) sA[w][t * 8 + j] = acc[j] * invd;
        }
        if (t < INDP) sS[w][t] = h0p[(size_t)node * INDP + t];
    }
    __syncthreads();
    if (node >= N) return;
    float acc = b[t];
#pragma unroll
    for (int k = 0; k < IND; ++k)
        acc += sA[w][k] * sWl[k * HIDD + t] + sS[w][k] * sWr[k * HIDD + t];
    float val = fmaxf(acc, 0.0f);
    h1f[(size_t)node * HIDD + t] = val;
    h1h[(size_t)node * HIDD + t] = __float2half(val);
}

// fused gather-mean(h1h fp16, packed hfma2) + layer2 k-split + pooled atomic
__global__ __launch_bounds__(512) void agg_layer2(
        const float* __restrict__ h1f, const __half* __restrict__ h1h,
        const int2* __restrict__ rowseg, const int* __restrict__ csr,
        const int* __restrict__ batch,
        const float* __restrict__ W_l, const float* __restrict__ W_r,
        const float* __restrict__ b,
        float* __restrict__ pooled, float* __restrict__ cnt, int N) {
    __shared__ float sA[8][HIDD];
    __shared__ float sS[8][HIDD];
    __shared__ float sP[8][8][HIDD];
    int w = threadIdx.x >> 6, t = threadIdx.x & 63;
    int kb = w * 8;
    int node = blockIdx.x * 8 + w;
    if (node < N) {
        int2 seg = rowseg[node];
        int beg = seg.x, end = seg.y;
        int s = t >> 3, p = t & 7;
        __half2 a[4];
#pragma unroll
        for (int j = 0; j < 4; ++j) a[j] = __float2half2_rn(0.0f);
        for (int cb = beg; cb < end; cb += 32) {
            int e0 = cb + s, e1 = e0 + 8, e2 = e0 + 16, e3 = e0 + 24;
            int i0 = csr[min(e0, end - 1)];
            int i1 = csr[min(e1, end - 1)];
            int i2 = csr[min(e2, end - 1)];
            int i3 = csr[min(e3, end - 1)];
            __half2 m0 = __float2half2_rn((e0 < end) ? 1.f : 0.f);
            __half2 m1 = __float2half2_rn((e1 < end) ? 1.f : 0.f);
            __half2 m2 = __float2half2_rn((e2 < end) ? 1.f : 0.f);
            __half2 m3 = __float2half2_rn((e3 < end) ? 1.f : 0.f);
            const uint4 v0 = *(const uint4*)(h1h + (size_t)i0 * HIDD + p * 8);
            const uint4 v1 = *(const uint4*)(h1h + (size_t)i1 * HIDD + p * 8);
            const uint4 v2 = *(const uint4*)(h1h + (size_t)i2 * HIDD + p * 8);
            const uint4 v3 = *(const uint4*)(h1h + (size_t)i3 * HIDD + p * 8);
            a[0] = __hfma2(u2h2(v0.x), m0, a[0]);
            a[1] = __hfma2(u2h2(v0.y), m0, a[1]);
            a[2] = __hfma2(u2h2(v0.z), m0, a[2]);
            a[3] = __hfma2(u2h2(v0.w), m0, a[3]);
            a[0] = __hfma2(u2h2(v1.x), m1, a[0]);
            a[1] = __hfma2(u2h2(v1.y), m1, a[1]);
            a[2] = __hfma2(u2h2(v1.z), m1, a[2]);
            a[3] = __hfma2(u2h2(v1.w), m1, a[3]);
            a[0] = __hfma2(u2h2(v2.x), m2, a[0]);
            a[1] = __hfma2(u2h2(v2.y), m2, a[1]);
            a[2] = __hfma2(u2h2(v2.z), m2, a[2]);
            a[3] = __hfma2(u2h2(v2.w), m2, a[3]);
            a[0] = __hfma2(u2h2(v3.x), m3, a[0]);
            a[1] = __hfma2(u2h2(v3.y), m3, a[1]);
            a[2] = __hfma2(u2h2(v3.z), m3, a[2]);
            a[3] = __hfma2(u2h2(v3.w), m3, a[3]);
        }
        float acc[8];
#pragma unroll
        for (int j = 0; j < 4; ++j) {
            float2 f = __half22float2(a[j]);
            acc[2 * j] = f.x;
            acc[2 * j + 1] = f.y;
        }
#pragma unroll
        for (int m = 8; m < 64; m <<= 1) {
#pragma unroll
            for (int j = 0; j < 8; ++j) acc[j] += __shfl_xor(acc[j], m, 64);
        }
        float invd = 1.0f / fmaxf((float)(end - beg), 1.0f);
        if (t < 8) {
#pragma unroll
            for (int j = 0; j < 8; ++j) sA[w][t * 8 + j] = acc[j] * invd;
        }
        sS[w][t] = h1f[(size_t)node * HIDD + t];
    }
    // weights after gather (L2-hit, once per block)
    float wl[8], wr[8];
#pragma unroll
    for (int kk = 0; kk < 8; ++kk) {
        wl[kk] = W_l[(kb + kk) * HIDD + t];
        wr[kk] = W_r[(kb + kk) * HIDD + t];
    }
    __syncthreads();
#pragma unroll
    for (int n = 0; n < 8; ++n) {
        const float4* pa = (const float4*)(&sA[n][kb]);
        const float4* ps = (const float4*)(&sS[n][kb]);
        float4 a0 = pa[0], a1 = pa[1], s0 = ps[0], s1 = ps[1];
        float acc;
        acc  = a0.x * wl[0] + a0.y * wl[1] + a0.z * wl[2] + a0.w * wl[3];
        acc += a1.x * wl[4] + a1.y * wl[5] + a1.z * wl[6] + a1.w * wl[7];
        acc += s0.x * wr[0] + s0.y * wr[1] + s0.z * wr[2] + s0.w * wr[3];
        acc += s1.x * wr[4] + s1.y * wr[5] + s1.z * wr[6] + s1.w * wr[7];
        sP[w][n][t] = acc;
    }
    __syncthreads();
    if (node >= N) return;
    float v = b[t];
#pragma unroll
    for (int j = 0; j < 8; ++j) v += sP[j][w][t];
    float val = fmaxf(v, 0.0f);
    int g = batch[node];
    atomicAdd(pooled + (size_t)g * HIDD + t, val);
    if (t == 0) atomicAdd(cnt + g, 1.0f);
}

__global__ void final_k(const float* __restrict__ pooled, const float* __restrict__ cnt,
                        const float* __restrict__ W, const float* __restrict__ bl,
                        float* __restrict__ out, int G) {
    int g = blockIdx.x;
    if (g >= G) return;
    int t = threadIdx.x;
    float invc = 1.0f / fmaxf(cnt[g], 1.0f);
    float v = pooled[(size_t)g * HIDD + t] * invc * W[t];
#pragma unroll
    for (int o = 32; o > 0; o >>= 1) v += __shfl_down(v, o, 64);
    if (t == 0) out[g] = v + bl[0];
}

extern "C" void kernel_launch(void* const* d_in, const int* in_sizes, int n_in,
                              void* d_out, int out_size, void* d_ws, size_t ws_size,
                              hipStream_t stream) {
    const float* x   = (const float*)d_in[0];
    const float* pos = (const float*)d_in[1];
    const int* ei    = (const int*)d_in[2];
    const int* batch = (const int*)d_in[3];
    const float* W1l = (const float*)d_in[4];
    const float* W1r = (const float*)d_in[5];
    const float* b1  = (const float*)d_in[6];
    const float* W2l = (const float*)d_in[7];
    const float* W2r = (const float*)d_in[8];
    const float* b2  = (const float*)d_in[9];
    const float* Wl  = (const float*)d_in[10];
    const float* bl  = (const float*)d_in[11];
    float* out = (float*)d_out;

    int N = in_sizes[3];
    int E = in_sizes[2] / 2;
    int G = out_size;
    int NB = (N + RB - 1) >> 9;
    int chunk = (E + BH_BLOCKS - 1) / BH_BLOCKS;   // 12500

    char* ws = (char*)d_ws;
    size_t off = 0;
    // ---- zero region (memset below) ----
    float* cnt = (float*)(ws + off);    off += (size_t)G * 4;
    float* pooled = (float*)(ws + off); off += (size_t)G * HIDD * 4;
    int* gcur = (int*)(ws + off);       off += (size_t)NB_MAX * 4;
    size_t zero_bytes = off;
    // ---- rest (fully written before read each call) ----
    off = (off + 255) & ~(size_t)255;
    int2* rowseg = (int2*)(ws + off);   off += (size_t)N * 8;
    uint* pairs = (uint*)(ws + off);    off += (size_t)NB * CAP * 4;
    int* csr    = (int*)(ws + off);     off += (size_t)NB * CAP * 4;
    off = (off + 255) & ~(size_t)255;
    float* h0p  = (float*)(ws + off);   off += (size_t)N * INDP * 4;
    off = (off + 255) & ~(size_t)255;
    __half* h0h = (__half*)(ws + off);  off += (size_t)N * INDP * 2;
    off = (off + 255) & ~(size_t)255;
    float* h1f  = (float*)(ws + off);   off += (size_t)N * HIDD * 4;
    off = (off + 255) & ~(size_t)255;
    __half* h1h = (__half*)(ws + off);  off += (size_t)N * HIDD * 2;

    hipMemsetAsync(d_ws, 0, zero_bytes, stream);

    bscat_fused<<<BH_BLOCKS, 1024, 0, stream>>>(x, pos, h0p, h0h, N,
                                                ei, gcur, pairs, E, NB, chunk);
    csr_build<<<NB, 1024, 0, stream>>>(pairs, gcur, rowseg, csr, N);
    agg_layer1<<<(N + 7) / 8, 512, 0, stream>>>(h0p, h0h, rowseg, csr, W1l, W1r, b1,
                                                h1f, h1h, N);
    agg_layer2<<<(N + 7) / 8, 512, 0, stream>>>(h1f, h1h, rowseg, csr, batch,
                                                W2l, W2r, b2, pooled, cnt, N);
    final_k<<<G, 64, 0, stream>>>(pooled, cnt, Wl, bl, out, G);
}

// Round 15
// 322.331 us; speedup vs baseline: 1.0076x; 1.0076x over previous
//
#include <hip/hip_runtime.h>
#include <hip/hip_fp16.h>

#define IND 14
#define INDP 16
#define HIDD 64
#define RB 512          // nodes per bucket (shift 9)
#define NB_MAX 256
#define BH_BLOCKS 256   // fewer, fatter blocks -> long per-bucket write runs
#define CAP 18432       // per-bucket pairs/csr capacity (mean 16384, sigma 128)
#define ROW1 20         // padded row stride for layer1 LDS tiles
#define DSTS (13 * 1024) // LDS dst-cache slots (chunk = 12500 -> 13 iters x 1024)

typedef unsigned int uint;
typedef unsigned short ushort;

__device__ __forceinline__ __half2 u2h2(uint u) { return *reinterpret_cast<__half2*>(&u); }

// fused: build h0p/h0h + single-pass bucket scatter (dst cached in LDS)
__global__ __launch_bounds__(1024) void bscat_fused(
        const float* __restrict__ x, const float* __restrict__ pos,
        float* __restrict__ h0p, __half* __restrict__ h0h, int N,
        const int* __restrict__ ei, int* __restrict__ gcur,
        uint* __restrict__ pairs, int E, int NB, int chunk) {
    __shared__ int cntS[NB_MAX];
    __shared__ int baseS[NB_MAX];
    __shared__ int dstS[DSTS];
    int tot = N * INDP;
    for (int i = blockIdx.x * 1024 + threadIdx.x; i < tot; i += BH_BLOCKS * 1024) {
        int n = i >> 4, d = i & 15;
        float v = 0.0f;
        if (d < 11) v = x[n * 11 + d];
        else if (d < 14) v = pos[n * 3 + (d - 11)];
        h0p[i] = v;
        h0h[i] = __float2half(v);
    }
    if (threadIdx.x < NB_MAX) cntS[threadIdx.x] = 0;
    __syncthreads();
    int start = blockIdx.x * chunk;
    int end = min(start + chunk, E);
    int it = 0;
    for (int e = start + threadIdx.x; e < end; e += 1024, ++it) {
        int d = ei[E + e];
        dstS[it * 1024 + threadIdx.x] = d;
        atomicAdd(&cntS[d >> 9], 1);
    }
    __syncthreads();
    if (threadIdx.x < NB) {
        int c = cntS[threadIdx.x];
        baseS[threadIdx.x] = c ? atomicAdd(&gcur[threadIdx.x], c) : 0;
        cntS[threadIdx.x] = 0;   // reuse as local cursor
    }
    __syncthreads();
    it = 0;
    for (int e = start + threadIdx.x; e < end; e += 1024, ++it) {
        int s = ei[e];
        int d = dstS[it * 1024 + threadIdx.x];
        int b = d >> 9;
        int p = atomicAdd(&cntS[b], 1) + baseS[b];
        pairs[(size_t)b * CAP + p] = ((uint)(d & (RB - 1)) << 17) | (uint)s;
    }
}

// block per bucket: LDS deg hist + scan -> rowseg(int2) + bucket-padded csr.
__global__ __launch_bounds__(1024) void csr_build(const uint* __restrict__ pairs,
                                                  const int* __restrict__ gcur,
                                                  int2* __restrict__ rowseg,
                                                  int* __restrict__ csr, int N) {
    __shared__ int s[RB];
    __shared__ int fillS[RB];
    __shared__ ushort localS[CAP];
    int b = blockIdx.x;
    int cnt = gcur[b];
    size_t base = (size_t)b * CAP;
    int t = threadIdx.x;
    if (t < RB) { s[t] = 0; fillS[t] = 0; }
    __syncthreads();
    for (int i = t; i < cnt; i += 1024) {
        int local = (int)(pairs[base + i] >> 17);
        localS[i] = (ushort)local;
        atomicAdd(&s[local], 1);
    }
    __syncthreads();
    for (int off = 1; off < RB; off <<= 1) {
        int v = 0;
        if (t < RB && t >= off) v = s[t - off];
        __syncthreads();
        if (t < RB) s[t] += v;
        __syncthreads();
    }
    int node0 = b << 9;
    if (t < RB) {
        int node = node0 + t;
        if (node < N)
            rowseg[node] = make_int2((int)base + (t ? s[t - 1] : 0), (int)base + s[t]);
    }
    __syncthreads();
    for (int i = t; i < cnt; i += 1024) {
        int local = localS[i];
        int src = (int)(pairs[base + i] & 0x1FFFFu);
        int p = atomicAdd(&fillS[local], 1);
        int segbase = local ? s[local - 1] : 0;
        csr[base + segbase + p] = src;
    }
}

// fused gather-mean(h0h fp16, packed hfma2) + layer1 GEMM; wave per node
__global__ __launch_bounds__(512) void agg_layer1(
        const float* __restrict__ h0p, const __half* __restrict__ h0h,
        const int2* __restrict__ rowseg, const int* __restrict__ csr,
        const float* __restrict__ W_l, const float* __restrict__ W_r,
        const float* __restrict__ b, float* __restrict__ h1f,
        __half* __restrict__ h1h, int N) {
    __shared__ float sWl[IND * HIDD];
    __shared__ float sWr[IND * HIDD];
    __shared__ float sA[8][ROW1];
    __shared__ float sS[8][ROW1];
    for (int i = threadIdx.x; i < IND * HIDD; i += 512) {
        sWl[i] = W_l[i];
        sWr[i] = W_r[i];
    }
    int w = threadIdx.x >> 6, t = threadIdx.x & 63;
    int node = blockIdx.x * 8 + w;
    if (node < N) {
        int2 seg = rowseg[node];
        int beg = seg.x, end = seg.y;
        int s = t >> 1, hf = t & 1;
        __half2 a[4];
#pragma unroll
        for (int j = 0; j < 4; ++j) a[j] = __float2half2_rn(0.0f);
        for (int cb = beg; cb < end; cb += 64) {
            int e0 = cb + s, e1 = e0 + 32;
            int i0 = csr[min(e0, end - 1)];
            int i1 = csr[min(e1, end - 1)];
            __half2 m0 = __float2half2_rn((e0 < end) ? 1.f : 0.f);
            __half2 m1 = __float2half2_rn((e1 < end) ? 1.f : 0.f);
            const uint4 v0 = *(const uint4*)(h0h + (size_t)i0 * INDP + hf * 8);
            const uint4 v1 = *(const uint4*)(h0h + (size_t)i1 * INDP + hf * 8);
            a[0] = __hfma2(u2h2(v0.x), m0, a[0]);
            a[1] = __hfma2(u2h2(v0.y), m0, a[1]);
            a[2] = __hfma2(u2h2(v0.z), m0, a[2]);
            a[3] = __hfma2(u2h2(v0.w), m0, a[3]);
            a[0] = __hfma2(u2h2(v1.x), m1, a[0]);
            a[1] = __hfma2(u2h2(v1.y), m1, a[1]);
            a[2] = __hfma2(u2h2(v1.z), m1, a[2]);
            a[3] = __hfma2(u2h2(v1.w), m1, a[3]);
        }
        float acc[8];
#pragma unroll
        for (int j = 0; j < 4; ++j) {
            float2 f = __half22float2(a[j]);
            acc[2 * j] = f.x;
            acc[2 * j + 1] = f.y;
        }
#pragma unroll
        for (int m = 2; m < 64; m <<= 1) {
#pragma unroll
            for (int j = 0; j < 8; ++j) acc[j] += __shfl_xor(acc[j], m, 64);
        }
        float invd = 1.0f / fmaxf((float)(end - beg), 1.0f);
        if (t < 2) {
#pragma unroll
            for (int j = 0; j < 8; ++j) sA[w][t * 8 + j] = acc[j] * invd;
        }
        if (t < INDP) sS[w][t] = h0p[(size_t)node * INDP + t];
    }
    __syncthreads();
    if (node >= N) return;
    float acc = b[t];
#pragma unroll
    for (int k = 0; k < IND; ++k)
        acc += sA[w][k] * sWl[k * HIDD + t] + sS[w][k] * sWr[k * HIDD + t];
    float val = fmaxf(acc, 0.0f);
    h1f[(size_t)node * HIDD + t] = val;
    h1h[(size_t)node * HIDD + t] = __float2half(val);
}

// fused gather-mean + layer2 + pooled atomic; TWO nodes per wave (2x MLP),
// 16 nodes/block, dense k-split in two 8-node passes (sP reused).
__global__ __launch_bounds__(512) void agg_layer2(
        const float* __restrict__ h1f, const __half* __restrict__ h1h,
        const int2* __restrict__ rowseg, const int* __restrict__ csr,
        const int* __restrict__ batch,
        const float* __restrict__ W_l, const float* __restrict__ W_r,
        const float* __restrict__ b,
        float* __restrict__ pooled, float* __restrict__ cnt, int N) {
    __shared__ float sA[16][HIDD];       // 4KB
    __shared__ float sS[16][HIDD];       // 4KB
    __shared__ float sP[8][8][HIDD];     // 16KB (reused across 2 dense passes)
    int w = threadIdx.x >> 6, t = threadIdx.x & 63;
    int kb = w * 8;
    int base = blockIdx.x * 16;
    int nA = base + 2 * w, nB = nA + 1;
    int begA = 0, endA = 0, begB = 0, endB = 0;
    if (nA < N) { int2 sg = rowseg[nA]; begA = sg.x; endA = sg.y; }
    if (nB < N) { int2 sg = rowseg[nB]; begB = sg.x; endB = sg.y; }
    {
        int s = t >> 3, p = t & 7;
        __half2 aA[4], aB[4];
#pragma unroll
        for (int j = 0; j < 4; ++j) { aA[j] = __float2half2_rn(0.f); aB[j] = __float2half2_rn(0.f); }
        int cbA = begA, cbB = begB;
        while (cbA < endA || cbB < endB) {
            bool doA = cbA < endA, doB = cbB < endB;   // wave-uniform
            int iA0, iA1, iA2, iA3, iB0, iB1, iB2, iB3;
            if (doA) {
                int e0 = cbA + s;
                iA0 = csr[min(e0, endA - 1)];
                iA1 = csr[min(e0 + 8, endA - 1)];
                iA2 = csr[min(e0 + 16, endA - 1)];
                iA3 = csr[min(e0 + 24, endA - 1)];
            }
            if (doB) {
                int e0 = cbB + s;
                iB0 = csr[min(e0, endB - 1)];
                iB1 = csr[min(e0 + 8, endB - 1)];
                iB2 = csr[min(e0 + 16, endB - 1)];
                iB3 = csr[min(e0 + 24, endB - 1)];
            }
            if (doA) {
                int e0 = cbA + s;
                __half2 m0 = __float2half2_rn((e0 < endA) ? 1.f : 0.f);
                __half2 m1 = __float2half2_rn((e0 + 8 < endA) ? 1.f : 0.f);
                __half2 m2 = __float2half2_rn((e0 + 16 < endA) ? 1.f : 0.f);
                __half2 m3 = __float2half2_rn((e0 + 24 < endA) ? 1.f : 0.f);
                const uint4 v0 = *(const uint4*)(h1h + (size_t)iA0 * HIDD + p * 8);
                const uint4 v1 = *(const uint4*)(h1h + (size_t)iA1 * HIDD + p * 8);
                const uint4 v2 = *(const uint4*)(h1h + (size_t)iA2 * HIDD + p * 8);
                const uint4 v3 = *(const uint4*)(h1h + (size_t)iA3 * HIDD + p * 8);
                aA[0] = __hfma2(u2h2(v0.x), m0, aA[0]); aA[1] = __hfma2(u2h2(v0.y), m0, aA[1]);
                aA[2] = __hfma2(u2h2(v0.z), m0, aA[2]); aA[3] = __hfma2(u2h2(v0.w), m0, aA[3]);
                aA[0] = __hfma2(u2h2(v1.x), m1, aA[0]); aA[1] = __hfma2(u2h2(v1.y), m1, aA[1]);
                aA[2] = __hfma2(u2h2(v1.z), m1, aA[2]); aA[3] = __hfma2(u2h2(v1.w), m1, aA[3]);
                aA[0] = __hfma2(u2h2(v2.x), m2, aA[0]); aA[1] = __hfma2(u2h2(v2.y), m2, aA[1]);
                aA[2] = __hfma2(u2h2(v2.z), m2, aA[2]); aA[3] = __hfma2(u2h2(v2.w), m2, aA[3]);
                aA[0] = __hfma2(u2h2(v3.x), m3, aA[0]); aA[1] = __hfma2(u2h2(v3.y), m3, aA[1]);
                aA[2] = __hfma2(u2h2(v3.z), m3, aA[2]); aA[3] = __hfma2(u2h2(v3.w), m3, aA[3]);
            }
            if (doB) {
                int e0 = cbB + s;
                __half2 m0 = __float2half2_rn((e0 < endB) ? 1.f : 0.f);
                __half2 m1 = __float2half2_rn((e0 + 8 < endB) ? 1.f : 0.f);
                __half2 m2 = __float2half2_rn((e0 + 16 < endB) ? 1.f : 0.f);
                __half2 m3 = __float2half2_rn((e0 + 24 < endB) ? 1.f : 0.f);
                const uint4 v0 = *(const uint4*)(h1h + (size_t)iB0 * HIDD + p * 8);
                const uint4 v1 = *(const uint4*)(h1h + (size_t)iB1 * HIDD + p * 8);
                const uint4 v2 = *(const uint4*)(h1h + (size_t)iB2 * HIDD + p * 8);
                const uint4 v3 = *(const uint4*)(h1h + (size_t)iB3 * HIDD + p * 8);
                aB[0] = __hfma2(u2h2(v0.x), m0, aB[0]); aB[1] = __hfma2(u2h2(v0.y), m0, aB[1]);
                aB[2] = __hfma2(u2h2(v0.z), m0, aB[2]); aB[3] = __hfma2(u2h2(v0.w), m0, aB[3]);
                aB[0] = __hfma2(u2h2(v1.x), m1, aB[0]); aB[1] = __hfma2(u2h2(v1.y), m1, aB[1]);
                aB[2] = __hfma2(u2h2(v1.z), m1, aB[2]); aB[3] = __hfma2(u2h2(v1.w), m1, aB[3]);
                aB[0] = __hfma2(u2h2(v2.x), m2, aB[0]); aB[1] = __hfma2(u2h2(v2.y), m2, aB[1]);
                aB[2] = __hfma2(u2h2(v2.z), m2, aB[2]); aB[3] = __hfma2(u2h2(v2.w), m2, aB[3]);
                aB[0] = __hfma2(u2h2(v3.x), m3, aB[0]); aB[1] = __hfma2(u2h2(v3.y), m3, aB[1]);
                aB[2] = __hfma2(u2h2(v3.z), m3, aB[2]); aB[3] = __hfma2(u2h2(v3.w), m3, aB[3]);
            }
            cbA += 32;
            cbB += 32;
        }
        float accA[8], accB[8];
#pragma unroll
        for (int j = 0; j < 4; ++j) {
            float2 fA = __half22float2(aA[j]);
            float2 fB = __half22float2(aB[j]);
            accA[2 * j] = fA.x; accA[2 * j + 1] = fA.y;
            accB[2 * j] = fB.x; accB[2 * j + 1] = fB.y;
        }
#pragma unroll
        for (int m = 8; m < 64; m <<= 1) {
#pragma unroll
            for (int j = 0; j < 8; ++j) {
                accA[j] += __shfl_xor(accA[j], m, 64);
                accB[j] += __shfl_xor(accB[j], m, 64);
            }
        }
        float invdA = 1.0f / fmaxf((float)(endA - begA), 1.0f);
        float invdB = 1.0f / fmaxf((float)(endB - begB), 1.0f);
        if (t < 8) {
#pragma unroll
            for (int j = 0; j < 8; ++j) {
                sA[2 * w][t * 8 + j] = accA[j] * invdA;
                sA[2 * w + 1][t * 8 + j] = accB[j] * invdB;
            }
        }
        sS[2 * w][t] = (nA < N) ? h1f[(size_t)nA * HIDD + t] : 0.f;
        sS[2 * w + 1][t] = (nB < N) ? h1f[(size_t)nB * HIDD + t] : 0.f;
    }
    // weights (L2-hit, once per block)
    float wl[8], wr[8];
#pragma unroll
    for (int kk = 0; kk < 8; ++kk) {
        wl[kk] = W_l[(kb + kk) * HIDD + t];
        wr[kk] = W_r[(kb + kk) * HIDD + t];
    }
    float bt = b[t];
    __syncthreads();
    // dense pass A: nodes base+0..7
#pragma unroll
    for (int n = 0; n < 8; ++n) {
        const float4* pa = (const float4*)(&sA[n][kb]);
        const float4* ps = (const float4*)(&sS[n][kb]);
        float4 a0 = pa[0], a1 = pa[1], s0 = ps[0], s1 = ps[1];
        float acc;
        acc  = a0.x * wl[0] + a0.y * wl[1] + a0.z * wl[2] + a0.w * wl[3];
        acc += a1.x * wl[4] + a1.y * wl[5] + a1.z * wl[6] + a1.w * wl[7];
        acc += s0.x * wr[0] + s0.y * wr[1] + s0.z * wr[2] + s0.w * wr[3];
        acc += s1.x * wr[4] + s1.y * wr[5] + s1.z * wr[6] + s1.w * wr[7];
        sP[w][n][t] = acc;
    }
    __syncthreads();
    {
        int nodeE = base + w;
        if (nodeE < N) {
            float v = bt;
#pragma unroll
            for (int j = 0; j < 8; ++j) v += sP[j][w][t];
            float val = fmaxf(v, 0.0f);
            int g = batch[nodeE];
            atomicAdd(pooled + (size_t)g * HIDD + t, val);
            if (t == 0) atomicAdd(cnt + g, 1.0f);
        }
    }
    __syncthreads();
    // dense pass B: nodes base+8..15
#pragma unroll
    for (int n = 0; n < 8; ++n) {
        const float4* pa = (const float4*)(&sA[8 + n][kb]);
        const float4* ps = (const float4*)(&sS[8 + n][kb]);
        float4 a0 = pa[0], a1 = pa[1], s0 = ps[0], s1 = ps[1];
        float acc;
        acc  = a0.x * wl[0] + a0.y * wl[1] + a0.z * wl[2] + a0.w * wl[3];
        acc += a1.x * wl[4] + a1.y * wl[5] + a1.z * wl[6] + a1.w * wl[7];
        acc += s0.x * wr[0] + s0.y * wr[1] + s0.z * wr[2] + s0.w * wr[3];
        acc += s1.x * wr[4] + s1.y * wr[5] + s1.z * wr[6] + s1.w * wr[7];
        sP[w][n][t] = acc;
    }
    __syncthreads();
    {
        int nodeE = base + 8 + w;
        if (nodeE < N) {
            float v = bt;
#pragma unroll
            for (int j = 0; j < 8; ++j) v += sP[j][w][t];
            float val = fmaxf(v, 0.0f);
            int g = batch[nodeE];
            atomicAdd(pooled + (size_t)g * HIDD + t, val);
            if (t == 0) atomicAdd(cnt + g, 1.0f);
        }
    }
}

__global__ void final_k(const float* __restrict__ pooled, const float* __restrict__ cnt,
                        const float* __restrict__ W, const float* __restrict__ bl,
                        float* __restrict__ out, int G) {
    int g = blockIdx.x;
    if (g >= G) return;
    int t = threadIdx.x;
    float invc = 1.0f / fmaxf(cnt[g], 1.0f);
    float v = pooled[(size_t)g * HIDD + t] * invc * W[t];
#pragma unroll
    for (int o = 32; o > 0; o >>= 1) v += __shfl_down(v, o, 64);
    if (t == 0) out[g] = v + bl[0];
}

extern "C" void kernel_launch(void* const* d_in, const int* in_sizes, int n_in,
                              void* d_out, int out_size, void* d_ws, size_t ws_size,
                              hipStream_t stream) {
    const float* x   = (const float*)d_in[0];
    const float* pos = (const float*)d_in[1];
    const int* ei    = (const int*)d_in[2];
    const int* batch = (const int*)d_in[3];
    const float* W1l = (const float*)d_in[4];
    const float* W1r = (const float*)d_in[5];
    const float* b1  = (const float*)d_in[6];
    const float* W2l = (const float*)d_in[7];
    const float* W2r = (const float*)d_in[8];
    const float* b2  = (const float*)d_in[9];
    const float* Wl  = (const float*)d_in[10];
    const float* bl  = (const float*)d_in[11];
    float* out = (float*)d_out;

    int N = in_sizes[3];
    int E = in_sizes[2] / 2;
    int G = out_size;
    int NB = (N + RB - 1) >> 9;
    int chunk = (E + BH_BLOCKS - 1) / BH_BLOCKS;   // 12500

    char* ws = (char*)d_ws;
    size_t off = 0;
    // ---- zero region (memset below) ----
    float* cnt = (float*)(ws + off);    off += (size_t)G * 4;
    float* pooled = (float*)(ws + off); off += (size_t)G * HIDD * 4;
    int* gcur = (int*)(ws + off);       off += (size_t)NB_MAX * 4;
    size_t zero_bytes = off;
    // ---- rest (fully written before read each call) ----
    off = (off + 255) & ~(size_t)255;
    int2* rowseg = (int2*)(ws + off);   off += (size_t)N * 8;
    uint* pairs = (uint*)(ws + off);    off += (size_t)NB * CAP * 4;
    int* csr    = (int*)(ws + off);     off += (size_t)NB * CAP * 4;
    off = (off + 255) & ~(size_t)255;
    float* h0p  = (float*)(ws + off);   off += (size_t)N * INDP * 4;
    off = (off + 255) & ~(size_t)255;
    __half* h0h = (__half*)(ws + off);  off += (size_t)N * INDP * 2;
    off = (off + 255) & ~(size_t)255;
    float* h1f  = (float*)(ws + off);   off += (size_t)N * HIDD * 4;
    off = (off + 255) & ~(size_t)255;
    __half* h1h = (__half*)(ws + off);  off += (size_t)N * HIDD * 2;

    hipMemsetAsync(d_ws, 0, zero_bytes, stream);

    bscat_fused<<<BH_BLOCKS, 1024, 0, stream>>>(x, pos, h0p, h0h, N,
                                                ei, gcur, pairs, E, NB, chunk);
    csr_build<<<NB, 1024, 0, stream>>>(pairs, gcur, rowseg, csr, N);
    agg_layer1<<<(N + 7) / 8, 512, 0, stream>>>(h0p, h0h, rowseg, csr, W1l, W1r, b1,
                                                h1f, h1h, N);
    agg_layer2<<<(N + 15) / 16, 512, 0, stream>>>(h1f, h1h, rowseg, csr, batch,
                                                  W2l, W2r, b2, pooled, cnt, N);
    final_k<<<G, 64, 0, stream>>>(pooled, cnt, Wl, bl, out, G);
}

// Round 16
// 320.769 us; speedup vs baseline: 1.0125x; 1.0049x over previous
//
#include <hip/hip_runtime.h>
#include <hip/hip_fp16.h>

#define IND 14
#define INDP 16
#define HIDD 64
#define RB 512          // nodes per bucket (shift 9)
#define NB_MAX 256
#define BH_BLOCKS 256
#define CAP 18432       // per-bucket pairs/csr capacity (mean 16384, sigma 128)
#define ROW1 20
#define DSTS (13 * 1024)

typedef unsigned int uint;
typedef unsigned short ushort;

__device__ __forceinline__ __half2 u2h2(uint u) { return *reinterpret_cast<__half2*>(&u); }

// fused: build h0h (fp16 only) + single-pass bucket scatter (dst cached in LDS)
__global__ __launch_bounds__(1024) void bscat_fused(
        const float* __restrict__ x, const float* __restrict__ pos,
        __half* __restrict__ h0h, int N,
        const int* __restrict__ ei, int* __restrict__ gcur,
        uint* __restrict__ pairs, int E, int NB, int chunk) {
    __shared__ int cntS[NB_MAX];
    __shared__ int baseS[NB_MAX];
    __shared__ int dstS[DSTS];
    int tot = N * INDP;
    for (int i = blockIdx.x * 1024 + threadIdx.x; i < tot; i += BH_BLOCKS * 1024) {
        int n = i >> 4, d = i & 15;
        float v = 0.0f;
        if (d < 11) v = x[n * 11 + d];
        else if (d < 14) v = pos[n * 3 + (d - 11)];
        h0h[i] = __float2half(v);
    }
    if (threadIdx.x < NB_MAX) cntS[threadIdx.x] = 0;
    __syncthreads();
    int start = blockIdx.x * chunk;
    int end = min(start + chunk, E);
    int it = 0;
    for (int e = start + threadIdx.x; e < end; e += 1024, ++it) {
        int d = ei[E + e];
        dstS[it * 1024 + threadIdx.x] = d;
        atomicAdd(&cntS[d >> 9], 1);
    }
    __syncthreads();
    if (threadIdx.x < NB) {
        int c = cntS[threadIdx.x];
        baseS[threadIdx.x] = c ? atomicAdd(&gcur[threadIdx.x], c) : 0;
        cntS[threadIdx.x] = 0;   // reuse as local cursor
    }
    __syncthreads();
    it = 0;
    for (int e = start + threadIdx.x; e < end; e += 1024, ++it) {
        int s = ei[e];
        int d = dstS[it * 1024 + threadIdx.x];
        int b = d >> 9;
        int p = atomicAdd(&cntS[b], 1) + baseS[b];
        pairs[(size_t)b * CAP + p] = ((uint)(d & (RB - 1)) << 17) | (uint)s;
    }
}

// block per bucket: LDS deg hist + scan -> rowseg(int2) + bucket-padded csr.
__global__ __launch_bounds__(1024) void csr_build(const uint* __restrict__ pairs,
                                                  const int* __restrict__ gcur,
                                                  int2* __restrict__ rowseg,
                                                  int* __restrict__ csr, int N) {
    __shared__ int s[RB];
    __shared__ int fillS[RB];
    __shared__ ushort localS[CAP];
    int b = blockIdx.x;
    int cnt = gcur[b];
    size_t base = (size_t)b * CAP;
    int t = threadIdx.x;
    if (t < RB) { s[t] = 0; fillS[t] = 0; }
    __syncthreads();
    for (int i = t; i < cnt; i += 1024) {
        int local = (int)(pairs[base + i] >> 17);
        localS[i] = (ushort)local;
        atomicAdd(&s[local], 1);
    }
    __syncthreads();
    for (int off = 1; off < RB; off <<= 1) {
        int v = 0;
        if (t < RB && t >= off) v = s[t - off];
        __syncthreads();
        if (t < RB) s[t] += v;
        __syncthreads();
    }
    int node0 = b << 9;
    if (t < RB) {
        int node = node0 + t;
        if (node < N)
            rowseg[node] = make_int2((int)base + (t ? s[t - 1] : 0), (int)base + s[t]);
    }
    __syncthreads();
    for (int i = t; i < cnt; i += 1024) {
        int local = localS[i];
        int src = (int)(pairs[base + i] & 0x1FFFFu);
        int p = atomicAdd(&fillS[local], 1);
        int segbase = local ? s[local - 1] : 0;
        csr[base + segbase + p] = src;
    }
}

// fused gather-mean(h0h fp16) + layer1 GEMM; wave per node; self term from h0h
__global__ __launch_bounds__(512) void agg_layer1(
        const __half* __restrict__ h0h,
        const int2* __restrict__ rowseg, const int* __restrict__ csr,
        const float* __restrict__ W_l, const float* __restrict__ W_r,
        const float* __restrict__ b, __half* __restrict__ h1h, int N) {
    __shared__ float sWl[IND * HIDD];
    __shared__ float sWr[IND * HIDD];
    __shared__ float sA[8][ROW1];
    __shared__ float sS[8][ROW1];
    for (int i = threadIdx.x; i < IND * HIDD; i += 512) {
        sWl[i] = W_l[i];
        sWr[i] = W_r[i];
    }
    int w = threadIdx.x >> 6, t = threadIdx.x & 63;
    int node = blockIdx.x * 8 + w;
    if (node < N) {
        int2 seg = rowseg[node];
        int beg = seg.x, end = seg.y;
        int s = t >> 1, hf = t & 1;
        __half2 a[4];
#pragma unroll
        for (int j = 0; j < 4; ++j) a[j] = __float2half2_rn(0.0f);
        for (int cb = beg; cb < end; cb += 64) {
            int e0 = cb + s, e1 = e0 + 32;
            int i0 = csr[min(e0, end - 1)];
            int i1 = csr[min(e1, end - 1)];
            __half2 m0 = __float2half2_rn((e0 < end) ? 1.f : 0.f);
            __half2 m1 = __float2half2_rn((e1 < end) ? 1.f : 0.f);
            const uint4 v0 = *(const uint4*)(h0h + (size_t)i0 * INDP + hf * 8);
            const uint4 v1 = *(const uint4*)(h0h + (size_t)i1 * INDP + hf * 8);
            a[0] = __hfma2(u2h2(v0.x), m0, a[0]);
            a[1] = __hfma2(u2h2(v0.y), m0, a[1]);
            a[2] = __hfma2(u2h2(v0.z), m0, a[2]);
            a[3] = __hfma2(u2h2(v0.w), m0, a[3]);
            a[0] = __hfma2(u2h2(v1.x), m1, a[0]);
            a[1] = __hfma2(u2h2(v1.y), m1, a[1]);
            a[2] = __hfma2(u2h2(v1.z), m1, a[2]);
            a[3] = __hfma2(u2h2(v1.w), m1, a[3]);
        }
        float acc[8];
#pragma unroll
        for (int j = 0; j < 4; ++j) {
            float2 f = __half22float2(a[j]);
            acc[2 * j] = f.x;
            acc[2 * j + 1] = f.y;
        }
#pragma unroll
        for (int m = 2; m < 64; m <<= 1) {
#pragma unroll
            for (int j = 0; j < 8; ++j) acc[j] += __shfl_xor(acc[j], m, 64);
        }
        float invd = 1.0f / fmaxf((float)(end - beg), 1.0f);
        if (t < 2) {
#pragma unroll
            for (int j = 0; j < 8; ++j) sA[w][t * 8 + j] = acc[j] * invd;
        }
        if (t < INDP) sS[w][t] = __half2float(h0h[(size_t)node * INDP + t]);
    }
    __syncthreads();
    if (node >= N) return;
    float acc = b[t];
#pragma unroll
    for (int k = 0; k < IND; ++k)
        acc += sA[w][k] * sWl[k * HIDD + t] + sS[w][k] * sWr[k * HIDD + t];
    float val = fmaxf(acc, 0.0f);
    h1h[(size_t)node * HIDD + t] = __float2half(val);
}

// fused gather-mean(h1h fp16) + layer2 k-split + pooled atomic; self from h1h
__global__ __launch_bounds__(512) void agg_layer2(
        const __half* __restrict__ h1h,
        const int2* __restrict__ rowseg, const int* __restrict__ csr,
        const int* __restrict__ batch,
        const float* __restrict__ W_l, const float* __restrict__ W_r,
        const float* __restrict__ b,
        float* __restrict__ pooled, float* __restrict__ cnt, int N) {
    __shared__ float sA[8][HIDD];
    __shared__ float sS[8][HIDD];
    __shared__ float sP[8][8][HIDD];
    int w = threadIdx.x >> 6, t = threadIdx.x & 63;
    int kb = w * 8;
    int node = blockIdx.x * 8 + w;
    if (node < N) {
        int2 seg = rowseg[node];
        int beg = seg.x, end = seg.y;
        int s = t >> 3, p = t & 7;
        __half2 a[4];
#pragma unroll
        for (int j = 0; j < 4; ++j) a[j] = __float2half2_rn(0.0f);
        for (int cb = beg; cb < end; cb += 32) {
            int e0 = cb + s, e1 = e0 + 8, e2 = e0 + 16, e3 = e0 + 24;
            int i0 = csr[min(e0, end - 1)];
            int i1 = csr[min(e1, end - 1)];
            int i2 = csr[min(e2, end - 1)];
            int i3 = csr[min(e3, end - 1)];
            __half2 m0 = __float2half2_rn((e0 < end) ? 1.f : 0.f);
            __half2 m1 = __float2half2_rn((e1 < end) ? 1.f : 0.f);
            __half2 m2 = __float2half2_rn((e2 < end) ? 1.f : 0.f);
            __half2 m3 = __float2half2_rn((e3 < end) ? 1.f : 0.f);
            const uint4 v0 = *(const uint4*)(h1h + (size_t)i0 * HIDD + p * 8);
            const uint4 v1 = *(const uint4*)(h1h + (size_t)i1 * HIDD + p * 8);
            const uint4 v2 = *(const uint4*)(h1h + (size_t)i2 * HIDD + p * 8);
            const uint4 v3 = *(const uint4*)(h1h + (size_t)i3 * HIDD + p * 8);
            a[0] = __hfma2(u2h2(v0.x), m0, a[0]);
            a[1] = __hfma2(u2h2(v0.y), m0, a[1]);
            a[2] = __hfma2(u2h2(v0.z), m0, a[2]);
            a[3] = __hfma2(u2h2(v0.w), m0, a[3]);
            a[0] = __hfma2(u2h2(v1.x), m1, a[0]);
            a[1] = __hfma2(u2h2(v1.y), m1, a[1]);
            a[2] = __hfma2(u2h2(v1.z), m1, a[2]);
            a[3] = __hfma2(u2h2(v1.w), m1, a[3]);
            a[0] = __hfma2(u2h2(v2.x), m2, a[0]);
            a[1] = __hfma2(u2h2(v2.y), m2, a[1]);
            a[2] = __hfma2(u2h2(v2.z), m2, a[2]);
            a[3] = __hfma2(u2h2(v2.w), m2, a[3]);
            a[0] = __hfma2(u2h2(v3.x), m3, a[0]);
            a[1] = __hfma2(u2h2(v3.y), m3, a[1]);
            a[2] = __hfma2(u2h2(v3.z), m3, a[2]);
            a[3] = __hfma2(u2h2(v3.w), m3, a[3]);
        }
        float acc[8];
#pragma unroll
        for (int j = 0; j < 4; ++j) {
            float2 f = __half22float2(a[j]);
            acc[2 * j] = f.x;
            acc[2 * j + 1] = f.y;
        }
#pragma unroll
        for (int m = 8; m < 64; m <<= 1) {
#pragma unroll
            for (int j = 0; j < 8; ++j) acc[j] += __shfl_xor(acc[j], m, 64);
        }
        float invd = 1.0f / fmaxf((float)(end - beg), 1.0f);
        if (t < 8) {
#pragma unroll
            for (int j = 0; j < 8; ++j) sA[w][t * 8 + j] = acc[j] * invd;
        }
        sS[w][t] = __half2float(h1h[(size_t)node * HIDD + t]);
    }
    // weights after gather (L2-hit, once per block)
    float wl[8], wr[8];
#pragma unroll
    for (int kk = 0; kk < 8; ++kk) {
        wl[kk] = W_l[(kb + kk) * HIDD + t];
        wr[kk] = W_r[(kb + kk) * HIDD + t];
    }
    __syncthreads();
#pragma unroll
    for (int n = 0; n < 8; ++n) {
        const float4* pa = (const float4*)(&sA[n][kb]);
        const float4* ps = (const float4*)(&sS[n][kb]);
        float4 a0 = pa[0], a1 = pa[1], s0 = ps[0], s1 = ps[1];
        float acc;
        acc  = a0.x * wl[0] + a0.y * wl[1] + a0.z * wl[2] + a0.w * wl[3];
        acc += a1.x * wl[4] + a1.y * wl[5] + a1.z * wl[6] + a1.w * wl[7];
        acc += s0.x * wr[0] + s0.y * wr[1] + s0.z * wr[2] + s0.w * wr[3];
        acc += s1.x * wr[4] + s1.y * wr[5] + s1.z * wr[6] + s1.w * wr[7];
        sP[w][n][t] = acc;
    }
    __syncthreads();
    if (node >= N) return;
    float v = b[t];
#pragma unroll
    for (int j = 0; j < 8; ++j) v += sP[j][w][t];
    float val = fmaxf(v, 0.0f);
    int g = batch[node];
    atomicAdd(pooled + (size_t)g * HIDD + t, val);
    if (t == 0) atomicAdd(cnt + g, 1.0f);
}

__global__ void final_k(const float* __restrict__ pooled, const float* __restrict__ cnt,
                        const float* __restrict__ W, const float* __restrict__ bl,
                        float* __restrict__ out, int G) {
    int g = blockIdx.x;
    if (g >= G) return;
    int t = threadIdx.x;
    float invc = 1.0f / fmaxf(cnt[g], 1.0f);
    float v = pooled[(size_t)g * HIDD + t] * invc * W[t];
#pragma unroll
    for (int o = 32; o > 0; o >>= 1) v += __shfl_down(v, o, 64);
    if (t == 0) out[g] = v + bl[0];
}

extern "C" void kernel_launch(void* const* d_in, const int* in_sizes, int n_in,
                              void* d_out, int out_size, void* d_ws, size_t ws_size,
                              hipStream_t stream) {
    const float* x   = (const float*)d_in[0];
    const float* pos = (const float*)d_in[1];
    const int* ei    = (const int*)d_in[2];
    const int* batch = (const int*)d_in[3];
    const float* W1l = (const float*)d_in[4];
    const float* W1r = (const float*)d_in[5];
    const float* b1  = (const float*)d_in[6];
    const float* W2l = (const float*)d_in[7];
    const float* W2r = (const float*)d_in[8];
    const float* b2  = (const float*)d_in[9];
    const float* Wl  = (const float*)d_in[10];
    const float* bl  = (const float*)d_in[11];
    float* out = (float*)d_out;

    int N = in_sizes[3];
    int E = in_sizes[2] / 2;
    int G = out_size;
    int NB = (N + RB - 1) >> 9;
    int chunk = (E + BH_BLOCKS - 1) / BH_BLOCKS;   // 12500

    char* ws = (char*)d_ws;
    size_t off = 0;
    // ---- zero region (memset below) ----
    float* cnt = (float*)(ws + off);    off += (size_t)G * 4;
    float* pooled = (float*)(ws + off); off += (size_t)G * HIDD * 4;
    int* gcur = (int*)(ws + off);       off += (size_t)NB_MAX * 4;
    size_t zero_bytes = off;
    // ---- rest (fully written before read each call) ----
    off = (off + 255) & ~(size_t)255;
    int2* rowseg = (int2*)(ws + off);   off += (size_t)N * 8;
    uint* pairs = (uint*)(ws + off);    off += (size_t)NB * CAP * 4;
    int* csr    = (int*)(ws + off);     off += (size_t)NB * CAP * 4;
    off = (off + 255) & ~(size_t)255;
    __half* h0h = (__half*)(ws + off);  off += (size_t)N * INDP * 2;
    off = (off + 255) & ~(size_t)255;
    __half* h1h = (__half*)(ws + off);  off += (size_t)N * HIDD * 2;

    hipMemsetAsync(d_ws, 0, zero_bytes, stream);

    bscat_fused<<<BH_BLOCKS, 1024, 0, stream>>>(x, pos, h0h, N,
                                                ei, gcur, pairs, E, NB, chunk);
    csr_build<<<NB, 1024, 0, stream>>>(pairs, gcur, rowseg, csr, N);
    agg_layer1<<<(N + 7) / 8, 512, 0, stream>>>(h0h, rowseg, csr, W1l, W1r, b1, h1h, N);
    agg_layer2<<<(N + 7) / 8, 512, 0, stream>>>(h1h, rowseg, csr, batch,
                                                W2l, W2r, b2, pooled, cnt, N);
    final_k<<<G, 64, 0, stream>>>(pooled, cnt, Wl, bl, out, G);
}